// Round 1
// baseline (3934.603 us; speedup 1.0000x reference)
//
#include <hip/hip_runtime.h>
#include <math.h>

// ---------------------------------------------------------------------------
// Polytope projection via dual PGD, restructured:
//   M = I - eta*(A A^T)   [m,m]      (precomputed)
//   r = eta*(x A^T - b)   [B,m]      (precomputed)
//   lam <- relu(lam M + r)           (30 total; first is lam=relu(r))
//   out = x - lam A
// Power iteration (10 iters) reproduced faithfully to match reference eta.
// ---------------------------------------------------------------------------

#define BM 128
#define BN 64
#define BK 16

enum { EPI_G = 0, EPI_R = 1, EPI_ITER = 2, EPI_OUT = 3 };

// ---------------- small power-iteration kernels ----------------

__global__ void k_init_v(float* v) {
    v[threadIdx.x] = 0.03125f;  // 1/sqrt(1024)
}

__global__ void k_zero(float* p) {
    p[blockIdx.x * blockDim.x + threadIdx.x] = 0.f;
}

// w[row] = dot(A[row,:], v)   (grid = m blocks, 256 threads)
__global__ __launch_bounds__(256) void k_Av(const float* __restrict__ A,
                                            const float* __restrict__ v,
                                            float* __restrict__ w, int d) {
    int row = blockIdx.x;
    const float* ar = A + (size_t)row * d;
    float s = 0.f;
    for (int k = threadIdx.x; k < d; k += 256) s += ar[k] * v[k];
    __shared__ float red[256];
    red[threadIdx.x] = s;
    __syncthreads();
    for (int off = 128; off > 0; off >>= 1) {
        if (threadIdx.x < off) red[threadIdx.x] += red[threadIdx.x + off];
        __syncthreads();
    }
    if (threadIdx.x == 0) w[row] = red[0];
}

// w2[col] += sum_{i in chunk} A[i,col]*w1[i]   grid=(d/256, m/32)
__global__ __launch_bounds__(256) void k_ATw(const float* __restrict__ A,
                                             const float* __restrict__ w1,
                                             float* __restrict__ w2, int d) {
    int col = blockIdx.x * 256 + threadIdx.x;
    int i0 = blockIdx.y * 32;
    float s = 0.f;
#pragma unroll
    for (int i = 0; i < 32; ++i) s += A[(size_t)(i0 + i) * d + col] * w1[i0 + i];
    atomicAdd(&w2[col], s);
}

// v = w2 / (||w2|| + 1e-12)   (single block of 1024)
__global__ __launch_bounds__(1024) void k_norm_scale(const float* __restrict__ w2,
                                                     float* __restrict__ v) {
    __shared__ float red[1024];
    int t = threadIdx.x;
    float x = w2[t];
    red[t] = x * x;
    __syncthreads();
    for (int off = 512; off > 0; off >>= 1) {
        if (t < off) red[t] += red[t + off];
        __syncthreads();
    }
    float scale = 1.f / (sqrtf(red[0]) + 1e-12f);
    v[t] = x * scale;
}

// eta = 1.8 / dot(w1,w1)   (single block of 1024)
__global__ __launch_bounds__(1024) void k_eta(const float* __restrict__ w1,
                                              float* __restrict__ eta) {
    __shared__ float red[1024];
    int t = threadIdx.x;
    float x = w1[t];
    red[t] = x * x;
    __syncthreads();
    for (int off = 512; off > 0; off >>= 1) {
        if (t < off) red[t] += red[t + off];
        __syncthreads();
    }
    if (t == 0) eta[0] = 1.8f / red[0];
}

// ---------------- tiled f32 GEMM with fused epilogues ----------------
// C[M,N] = A[M,K] * (TRANSB ? B[N,K]^T : B[K,N]) with epilogue:
//  EPI_G   : C = (i==j) - eta*acc                           (M matrix)
//  EPI_R   : C = eta*(acc - b[j]); out2 = relu(C)           (r and lam0)
//  EPI_ITER: C = relu(acc + aux[i,j])                       (lam update)
//  EPI_OUT : C = aux[i,j] - acc                             (final out)

template <bool TRANSB, int EPI>
__global__ __launch_bounds__(256, 2) void k_gemm(
    const float* __restrict__ Am, const float* __restrict__ Bm,
    float* __restrict__ Cm, int Ndim, int Kdim,
    const float* __restrict__ eta_p, const float* __restrict__ bvec,
    const float* __restrict__ aux, float* __restrict__ out2) {
    __shared__ float As[BK][BM + 4];   // stride 132 floats (528B, 16B aligned)
    __shared__ float Bs[BK][BN + 4];   // stride 68 floats (272B, 16B aligned)

    const int tid = threadIdx.x;
    const int rowBase = blockIdx.x * BM;
    const int n0 = blockIdx.y * BN;
    const int tm = tid >> 4;    // 0..15
    const int tn = tid & 15;    // 0..15

    float acc[8][4];
#pragma unroll
    for (int i = 0; i < 8; ++i)
#pragma unroll
        for (int j = 0; j < 4; ++j) acc[i][j] = 0.f;

    for (int k0 = 0; k0 < Kdim; k0 += BK) {
        // A tile: 128 rows x 16 cols, 512 float4s, 2 per thread; store transposed
#pragma unroll
        for (int s = 0; s < 2; ++s) {
            int fid = tid + s * 256;
            int row = fid >> 2;
            int c4 = (fid & 3) * 4;
            float4 va = *(const float4*)(Am + (size_t)(rowBase + row) * Kdim + k0 + c4);
            As[c4 + 0][row] = va.x;
            As[c4 + 1][row] = va.y;
            As[c4 + 2][row] = va.z;
            As[c4 + 3][row] = va.w;
        }
        // B tile
        if (TRANSB) {
            // B is [N,K] row-major: 64 rows x 16 cols = 256 float4, 1/thread
            int row = tid >> 2;
            int c4 = (tid & 3) * 4;
            float4 vb = *(const float4*)(Bm + (size_t)(n0 + row) * Kdim + k0 + c4);
            Bs[c4 + 0][row] = vb.x;
            Bs[c4 + 1][row] = vb.y;
            Bs[c4 + 2][row] = vb.z;
            Bs[c4 + 3][row] = vb.w;
        } else {
            // B is [K,N] row-major: 16 rows x 64 cols = 256 float4, 1/thread
            int kk = tid >> 4;
            int n4 = (tid & 15) * 4;
            float4 vb = *(const float4*)(Bm + (size_t)(k0 + kk) * Ndim + n0 + n4);
            *(float4*)&Bs[kk][n4] = vb;
        }
        __syncthreads();

#pragma unroll
        for (int kk = 0; kk < BK; ++kk) {
            float a[8], bf[4];
            *(float4*)&a[0] = *(const float4*)&As[kk][tm * 4];
            *(float4*)&a[4] = *(const float4*)&As[kk][tm * 4 + 64];
            *(float4*)&bf[0] = *(const float4*)&Bs[kk][tn * 4];
#pragma unroll
            for (int i = 0; i < 8; ++i)
#pragma unroll
                for (int j = 0; j < 4; ++j) acc[i][j] = fmaf(a[i], bf[j], acc[i][j]);
        }
        __syncthreads();
    }

    const float eta = (EPI == EPI_G || EPI == EPI_R) ? eta_p[0] : 0.f;

#pragma unroll
    for (int ih = 0; ih < 2; ++ih)
#pragma unroll
        for (int i = 0; i < 4; ++i) {
            int gr = rowBase + tm * 4 + ih * 64 + i;
            int gc = n0 + tn * 4;
            size_t off = (size_t)gr * Ndim + gc;
            const float* ap = acc[ih * 4 + i];
            float4 res;
            if (EPI == EPI_G) {
                res.x = (gr == gc + 0 ? 1.f : 0.f) - eta * ap[0];
                res.y = (gr == gc + 1 ? 1.f : 0.f) - eta * ap[1];
                res.z = (gr == gc + 2 ? 1.f : 0.f) - eta * ap[2];
                res.w = (gr == gc + 3 ? 1.f : 0.f) - eta * ap[3];
            } else if (EPI == EPI_R) {
                float4 bv = *(const float4*)(bvec + gc);
                res.x = eta * (ap[0] - bv.x);
                res.y = eta * (ap[1] - bv.y);
                res.z = eta * (ap[2] - bv.z);
                res.w = eta * (ap[3] - bv.w);
                float4 l;
                l.x = fmaxf(res.x, 0.f);
                l.y = fmaxf(res.y, 0.f);
                l.z = fmaxf(res.z, 0.f);
                l.w = fmaxf(res.w, 0.f);
                *(float4*)(out2 + off) = l;
            } else if (EPI == EPI_ITER) {
                float4 rv = *(const float4*)(aux + off);
                res.x = fmaxf(ap[0] + rv.x, 0.f);
                res.y = fmaxf(ap[1] + rv.y, 0.f);
                res.z = fmaxf(ap[2] + rv.z, 0.f);
                res.w = fmaxf(ap[3] + rv.w, 0.f);
            } else {  // EPI_OUT
                float4 xv = *(const float4*)(aux + off);
                res.x = xv.x - ap[0];
                res.y = xv.y - ap[1];
                res.z = xv.z - ap[2];
                res.w = xv.w - ap[3];
            }
            *(float4*)(Cm + off) = res;
        }
}

// ---------------------------------------------------------------------------

extern "C" void kernel_launch(void* const* d_in, const int* in_sizes, int n_in,
                              void* d_out, int out_size, void* d_ws, size_t ws_size,
                              hipStream_t stream) {
    const float* x = (const float*)d_in[0];  // [B, d]
    const float* A = (const float*)d_in[1];  // [m, d]
    const float* b = (const float*)d_in[2];  // [m]

    const int m = in_sizes[2];
    const int d = in_sizes[1] / m;
    const int B = in_sizes[0] / d;

    float* out = (float*)d_out;

    // workspace layout (floats)
    float* wsf = (float*)d_ws;
    size_t o = 0;
    float* v = wsf + o;   o += d;
    float* w1 = wsf + o;  o += m;
    float* w2 = wsf + o;  o += d;
    float* eta = wsf + o; o += 64;            // scalar + pad
    o = (o + 255) & ~(size_t)255;
    float* Mm = wsf + o;  o += (size_t)m * m;  // I - eta*A A^T
    float* r = wsf + o;   o += (size_t)B * m;  // eta*(x A^T - b)
    float* lamA = wsf + o; o += (size_t)B * m; // lam ping buffer (pong = d_out)

    // ---- power iteration: eta = 1.8 / lambda_max(A A^T) ----
    k_init_v<<<1, d, 0, stream>>>(v);
    for (int it = 0; it < 10; ++it) {
        k_Av<<<m, 256, 0, stream>>>(A, v, w1, d);
        k_zero<<<d / 256, 256, 0, stream>>>(w2);
        k_ATw<<<dim3(d / 256, m / 32), 256, 0, stream>>>(A, w1, w2, d);
        k_norm_scale<<<1, d, 0, stream>>>(w2, v);
    }
    k_Av<<<m, 256, 0, stream>>>(A, v, w1, d);
    k_eta<<<1, m, 0, stream>>>(w1, eta);

    // ---- M = I - eta * (A A^T)  [m,m]  (NT gemm) ----
    k_gemm<true, EPI_G><<<dim3(m / BM, m / BN), 256, 0, stream>>>(
        A, A, Mm, m, d, eta, nullptr, nullptr, nullptr);

    // ---- r = eta*(x A^T - b); lam0 = relu(r) -> d_out  (NT gemm) ----
    k_gemm<true, EPI_R><<<dim3(B / BM, m / BN), 256, 0, stream>>>(
        x, A, r, m, d, eta, b, nullptr, out);

    // ---- 29 iterations: lam <- relu(lam M + r)  (NN gemm) ----
    // ping-pong: buffers {d_out, lamA}; step i: even -> d_out->lamA, odd -> lamA->d_out
    const float* lam_in = out;
    float* lam_out = lamA;
    for (int it = 0; it < 29; ++it) {
        k_gemm<false, EPI_ITER><<<dim3(B / BM, m / BN), 256, 0, stream>>>(
            lam_in, Mm, lam_out, m, m, nullptr, nullptr, r, nullptr);
        const float* t = lam_out;
        lam_out = (float*)lam_in;
        lam_in = t;
    }
    // 29 steps (odd) => final lam is in lamA, lam_in == lamA now.

    // ---- out = x - lam A  (NN gemm) ----
    k_gemm<false, EPI_OUT><<<dim3(B / BM, d / BN), 256, 0, stream>>>(
        lam_in, A, out, d, m, nullptr, nullptr, x, nullptr);
}

// Round 2
// 1075.510 us; speedup vs baseline: 3.6584x; 3.6584x over previous
//
#include <hip/hip_runtime.h>
#include <math.h>

// ---------------------------------------------------------------------------
// Polytope projection via dual PGD, restructured:
//   H = A A^T                        (fp16x2 MFMA GEMM)
//   eta = 1.8/lambda_max(H)          (power iteration on H, dir-equivalent)
//   M = I - eta*H  (SYMMETRIC)       (elementwise, split to f16 hi/lo)
//   r = eta*(x A^T - b)              (MFMA GEMM, f32-A-side convert-on-read)
//   lam <- relu(lam M + r)  x29      (fp16x2 MFMA GEMM, split fused in epi)
//   out = x - lam A                  (fp16x2 MFMA GEMM vs pre-split A^T)
// fp16x2 split (Ootomo): v = hi + lo/2048, 3 MFMAs/product, ~f32 precision.
// ---------------------------------------------------------------------------

typedef _Float16 f16x8 __attribute__((ext_vector_type(8)));
typedef _Float16 f16x4 __attribute__((ext_vector_type(4)));
typedef float f32x4 __attribute__((ext_vector_type(4)));

#define GLD16(G, L)                                                          \
  __builtin_amdgcn_global_load_lds(                                          \
      (const __attribute__((address_space(1))) void*)(const void*)(G),       \
      (__attribute__((address_space(3))) void*)(void*)(L), 16, 0, 0)

__device__ __forceinline__ void split_store(float v, size_t idx,
                                            _Float16* __restrict__ hp,
                                            _Float16* __restrict__ lp) {
    _Float16 h = (_Float16)v;
    hp[idx] = h;
    lp[idx] = (_Float16)((v - (float)h) * 2048.f);
}

// ---------------- elementwise split kernels ----------------

__global__ __launch_bounds__(256) void k_split(const float* __restrict__ A,
                                               _Float16* __restrict__ Ah,
                                               _Float16* __restrict__ Al) {
    size_t i4 = ((size_t)blockIdx.x * 256 + threadIdx.x) * 4;
    float4 v = *(const float4*)(A + i4);
    float va[4] = {v.x, v.y, v.z, v.w};
    f16x4 hh, ll;
#pragma unroll
    for (int e = 0; e < 4; ++e) {
        _Float16 h = (_Float16)va[e];
        hh[e] = h;
        ll[e] = (_Float16)((va[e] - (float)h) * 2048.f);
    }
    *(f16x4*)(Ah + i4) = hh;
    *(f16x4*)(Al + i4) = ll;
}

// M = I - eta*H, split
__global__ __launch_bounds__(256) void k_makeM(const float* __restrict__ H,
                                               const float* __restrict__ eta_p,
                                               _Float16* __restrict__ Mh,
                                               _Float16* __restrict__ Ml) {
    float eta = eta_p[0];
    size_t i4 = ((size_t)blockIdx.x * 256 + threadIdx.x) * 4;
    float4 v = *(const float4*)(H + i4);
    float va[4] = {v.x, v.y, v.z, v.w};
    int row = (int)(i4 >> 10);
    int col0 = (int)(i4 & 1023);
    f16x4 hh, ll;
#pragma unroll
    for (int e = 0; e < 4; ++e) {
        float mv = ((col0 + e) == row ? 1.f : 0.f) - eta * va[e];
        _Float16 h = (_Float16)mv;
        hh[e] = h;
        ll[e] = (_Float16)((mv - (float)h) * 2048.f);
    }
    *(f16x4*)(Mh + i4) = hh;
    *(f16x4*)(Ml + i4) = ll;
}

// A [1024,1024] -> AT split (AT[j][i] = A[i][j]) via 32x32 LDS tiles
__global__ __launch_bounds__(256) void k_tsplit(const float* __restrict__ A,
                                                _Float16* __restrict__ Th,
                                                _Float16* __restrict__ Tl) {
    __shared__ float ts[32][33];
    int i0 = blockIdx.x * 32, j0 = blockIdx.y * 32;
    int tr = threadIdx.x >> 3, tc4 = (threadIdx.x & 7) * 4;
    float4 v = *(const float4*)(A + (size_t)(i0 + tr) * 1024 + j0 + tc4);
    ts[tr][tc4] = v.x; ts[tr][tc4 + 1] = v.y;
    ts[tr][tc4 + 2] = v.z; ts[tr][tc4 + 3] = v.w;
    __syncthreads();
    f16x4 hh, ll;
#pragma unroll
    for (int e = 0; e < 4; ++e) {
        float x = ts[tc4 + e][tr];
        _Float16 h = (_Float16)x;
        hh[e] = h;
        ll[e] = (_Float16)((x - (float)h) * 2048.f);
    }
    *(f16x4*)(Th + (size_t)(j0 + tr) * 1024 + i0 + tc4) = hh;
    *(f16x4*)(Tl + (size_t)(j0 + tr) * 1024 + i0 + tc4) = ll;
}

// ---------------- power iteration on H (m-space, dir-equivalent) ----------

__global__ __launch_bounds__(256) void k_u0(const float* __restrict__ A,
                                            float* __restrict__ u) {
    int r = blockIdx.x * 16 + (threadIdx.x >> 4);
    int gq = threadIdx.x & 15;
    const float* ar = A + (size_t)r * 1024;
    float s = 0.f;
    for (int c = gq * 4; c < 1024; c += 64) {
        float4 v = *(const float4*)(ar + c);
        s += v.x + v.y + v.z + v.w;
    }
    s += __shfl_xor(s, 1, 16); s += __shfl_xor(s, 2, 16);
    s += __shfl_xor(s, 4, 16); s += __shfl_xor(s, 8, 16);
    if (gq == 0) u[r] = s * 0.03125f;  // * 1/sqrt(1024)
}

__global__ __launch_bounds__(256) void k_matvec(const float* __restrict__ H,
                                                const float* __restrict__ u,
                                                float* __restrict__ w) {
    int r = blockIdx.x * 16 + (threadIdx.x >> 4);
    int gq = threadIdx.x & 15;
    const float* hr = H + (size_t)r * 1024;
    float s = 0.f;
    for (int c = gq * 4; c < 1024; c += 64) {
        float4 hv = *(const float4*)(hr + c);
        float4 uv = *(const float4*)(u + c);
        s += hv.x * uv.x + hv.y * uv.y + hv.z * uv.z + hv.w * uv.w;
    }
    s += __shfl_xor(s, 1, 16); s += __shfl_xor(s, 2, 16);
    s += __shfl_xor(s, 4, 16); s += __shfl_xor(s, 8, 16);
    if (gq == 0) w[r] = s;
}

__global__ __launch_bounds__(1024) void k_normalize(const float* __restrict__ w,
                                                    float* __restrict__ u) {
    __shared__ float red[1024];
    int t = threadIdx.x;
    float x = w[t];
    red[t] = x * x;
    __syncthreads();
    for (int o = 512; o > 0; o >>= 1) {
        if (t < o) red[t] += red[t + o];
        __syncthreads();
    }
    u[t] = x / (sqrtf(red[0]) + 1e-12f);
}

// eta = 1.8 * (u.z) / (z.z)   with z = H u9   [lambda = ||z||^2/(u.z)]
__global__ __launch_bounds__(1024) void k_eta2(const float* __restrict__ z,
                                               const float* __restrict__ u,
                                               float* __restrict__ eta) {
    __shared__ float r1[1024], r2[1024];
    int t = threadIdx.x;
    float zv = z[t], uv = u[t];
    r1[t] = zv * zv;
    r2[t] = uv * zv;
    __syncthreads();
    for (int o = 512; o > 0; o >>= 1) {
        if (t < o) { r1[t] += r1[t + o]; r2[t] += r2[t + o]; }
        __syncthreads();
    }
    if (t == 0) eta[0] = 1.8f * r2[0] / r1[0];
}

// ---------------- fp16x2 split NT MFMA GEMM ----------------
// C[i][j] = sum_k Aop[i][k] * Bop[j][k];  tile 64x128, BK=64, 4 waves.
// EPI 0: fout = acc                         (H)
// EPI 1: r = eta*(acc - b[j]) -> fout; lam = relu(r) split   (AF32 A-side: x)
// EPI 2: lam = relu(acc + r[i][j]) split    (iteration)
// EPI 3: fout = x[i][j] - acc               (final out)

template <int EPI, bool AF32>
__global__ __launch_bounds__(256, 2) void k_mm(
    const float* __restrict__ Ag32,
    const _Float16* __restrict__ Agh, const _Float16* __restrict__ Agl,
    const _Float16* __restrict__ Bgh, const _Float16* __restrict__ Bgl,
    int Kdim, int Ndim,
    const float* __restrict__ eta_p, const float* __restrict__ bvec,
    const float* __restrict__ raux, float* __restrict__ fout,
    _Float16* __restrict__ lamh, _Float16* __restrict__ laml) {
    __shared__ __align__(16) char lds[49152];
    _Float16* tAh = (_Float16*)lds;            // 8KB   (fp16 path)
    _Float16* tAl = (_Float16*)(lds + 8192);   // 8KB
    float* tAf = (float*)lds;                  // 16KB  (AF32 path)
    _Float16* tBh = (_Float16*)(lds + 16384);  // 16KB
    _Float16* tBl = (_Float16*)(lds + 32768);  // 16KB

    const int tid = threadIdx.x;
    const int wid = tid >> 6, lane = tid & 63;
    const int wr = wid >> 1, wc = wid & 1;
    const int laneLo = lane & 15, g = lane >> 4, x7 = lane & 7;
    const int rowBase = blockIdx.x * 64;
    const int colBase = blockIdx.y * 128;

    // staging source element-offsets (chunk-XOR pre-swizzled; rule-21 pair)
    size_t aSrc[4];
    if constexpr (AF32) {
#pragma unroll
        for (int s = 0; s < 4; ++s) {
            int q = s * 256 + tid, r = q >> 4, c = q & 15, sc = c ^ (r & 7);
            aSrc[s] = (size_t)(rowBase + r) * Kdim + sc * 4;
        }
    } else {
#pragma unroll
        for (int s = 0; s < 2; ++s) {
            int q = s * 256 + tid, r = q >> 3, c = q & 7, sc = c ^ (r & 7);
            aSrc[s] = (size_t)(rowBase + r) * Kdim + sc * 8;
        }
    }
    size_t bSrc[4];
#pragma unroll
    for (int s = 0; s < 4; ++s) {
        int q = s * 256 + tid, r = q >> 3, c = q & 7, sc = c ^ (r & 7);
        bSrc[s] = (size_t)(colBase + r) * Kdim + sc * 8;
    }

    f32x4 acch[2][4], accm[2][4];
#pragma unroll
    for (int m = 0; m < 2; ++m)
#pragma unroll
        for (int n = 0; n < 4; ++n) {
            acch[m][n] = (f32x4)0.f;
            accm[m][n] = (f32x4)0.f;
        }

    for (int k0 = 0; k0 < Kdim; k0 += 64) {
        // ---- stage (global -> LDS, 16B, linear dest / pre-swizzled src) ----
        if constexpr (AF32) {
#pragma unroll
            for (int s = 0; s < 4; ++s)
                GLD16(Ag32 + aSrc[s] + k0, lds + ((s << 8) + (wid << 6)) * 16);
        } else {
#pragma unroll
            for (int s = 0; s < 2; ++s) {
                GLD16(Agh + aSrc[s] + k0, (char*)tAh + ((s << 8) + (wid << 6)) * 16);
                GLD16(Agl + aSrc[s] + k0, (char*)tAl + ((s << 8) + (wid << 6)) * 16);
            }
        }
#pragma unroll
        for (int s = 0; s < 4; ++s) {
            GLD16(Bgh + bSrc[s] + k0, (char*)tBh + ((s << 8) + (wid << 6)) * 16);
            GLD16(Bgl + bSrc[s] + k0, (char*)tBl + ((s << 8) + (wid << 6)) * 16);
        }
        __syncthreads();

        // ---- compute 2 k-subtiles of 32 ----
#pragma unroll
        for (int kk = 0; kk < 2; ++kk) {
            f16x8 ah[2], al[2], bh[4], bl[4];
            if constexpr (AF32) {
#pragma unroll
                for (int m = 0; m < 2; ++m) {
                    int rA = wr * 32 + m * 16 + laneLo;
                    int c0 = (kk << 3) + (g << 1);
                    float4 v0 = *(const float4*)(tAf + rA * 64 + ((c0 ^ x7) << 2));
                    float4 v1 = *(const float4*)(tAf + rA * 64 + (((c0 + 1) ^ x7) << 2));
                    float va[8] = {v0.x, v0.y, v0.z, v0.w, v1.x, v1.y, v1.z, v1.w};
#pragma unroll
                    for (int e = 0; e < 8; ++e) {
                        _Float16 h = (_Float16)va[e];
                        ah[m][e] = h;
                        al[m][e] = (_Float16)((va[e] - (float)h) * 2048.f);
                    }
                }
            } else {
#pragma unroll
                for (int m = 0; m < 2; ++m) {
                    int rA = wr * 32 + m * 16 + laneLo;
                    int off = rA * 64 + ((((kk << 2) + g) ^ x7) << 3);
                    ah[m] = *(const f16x8*)(tAh + off);
                    al[m] = *(const f16x8*)(tAl + off);
                }
            }
#pragma unroll
            for (int n = 0; n < 4; ++n) {
                int rB = wc * 64 + n * 16 + laneLo;
                int off = rB * 64 + ((((kk << 2) + g) ^ x7) << 3);
                bh[n] = *(const f16x8*)(tBh + off);
                bl[n] = *(const f16x8*)(tBl + off);
            }
#pragma unroll
            for (int m = 0; m < 2; ++m)
#pragma unroll
                for (int n = 0; n < 4; ++n) {
                    acch[m][n] = __builtin_amdgcn_mfma_f32_16x16x32_f16(
                        ah[m], bh[n], acch[m][n], 0, 0, 0);
                    accm[m][n] = __builtin_amdgcn_mfma_f32_16x16x32_f16(
                        ah[m], bl[n], accm[m][n], 0, 0, 0);
                    accm[m][n] = __builtin_amdgcn_mfma_f32_16x16x32_f16(
                        al[m], bh[n], accm[m][n], 0, 0, 0);
                }
        }
        __syncthreads();
    }

    // ---- epilogue ----
    float etav = 0.f;
    if (EPI == 1) etav = eta_p[0];
#pragma unroll
    for (int m = 0; m < 2; ++m)
#pragma unroll
        for (int n = 0; n < 4; ++n) {
            int col = colBase + wc * 64 + n * 16 + laneLo;
#pragma unroll
            for (int p = 0; p < 4; ++p) {
                int row = rowBase + wr * 32 + m * 16 + (g << 2) + p;
                size_t idx = (size_t)row * Ndim + col;
                float val = acch[m][n][p] + accm[m][n][p] * 4.8828125e-4f;
                if (EPI == 0) {
                    fout[idx] = val;
                } else if (EPI == 1) {
                    float rv = etav * (val - bvec[col]);
                    fout[idx] = rv;
                    split_store(fmaxf(rv, 0.f), idx, lamh, laml);
                } else if (EPI == 2) {
                    split_store(fmaxf(val + raux[idx], 0.f), idx, lamh, laml);
                } else {
                    fout[idx] = raux[idx] - val;
                }
            }
        }
}

// ---------------------------------------------------------------------------

extern "C" void kernel_launch(void* const* d_in, const int* in_sizes, int n_in,
                              void* d_out, int out_size, void* d_ws, size_t ws_size,
                              hipStream_t stream) {
    const float* x = (const float*)d_in[0];  // [B, d]
    const float* A = (const float*)d_in[1];  // [m, d]
    const float* b = (const float*)d_in[2];  // [m]

    const int m = in_sizes[2];           // 1024
    const int dd = in_sizes[1] / m;      // 1024
    const int Bn = in_sizes[0] / dd;     // 4096
    float* out = (float*)d_out;

    // workspace layout (bytes)
    char* w8 = (char*)d_ws;
    float* eta = (float*)w8;                         // 256 B
    float* u = (float*)(w8 + 256);                   // 4 KB
    float* wv = (float*)(w8 + 256 + 4096);           // 4 KB
    size_t off = 16384;
    float* H = (float*)(w8 + off);     off += (size_t)m * m * 4;   // 4 MB
    _Float16* Mh = (_Float16*)(w8 + off); off += (size_t)m * m * 2;
    _Float16* Ml = (_Float16*)(w8 + off); off += (size_t)m * m * 2;
    _Float16* Ah = (_Float16*)(w8 + off); off += (size_t)m * dd * 2;
    _Float16* Al = (_Float16*)(w8 + off); off += (size_t)m * dd * 2;
    _Float16* ATh = (_Float16*)(w8 + off); off += (size_t)m * dd * 2;
    _Float16* ATl = (_Float16*)(w8 + off); off += (size_t)m * dd * 2;
    float* r = (float*)(w8 + off);     off += (size_t)Bn * m * 4;  // 16 MB
    _Float16* l0h = (_Float16*)(w8 + off); off += (size_t)Bn * m * 2;
    _Float16* l0l = (_Float16*)(w8 + off); off += (size_t)Bn * m * 2;
    _Float16* l1h = (_Float16*)(w8 + off); off += (size_t)Bn * m * 2;
    _Float16* l1l = (_Float16*)(w8 + off); off += (size_t)Bn * m * 2;

    // ---- split A; transpose-split A ----
    k_split<<<(m * dd) / 1024, 256, 0, stream>>>(A, Ah, Al);
    k_tsplit<<<dim3(m / 32, dd / 32), 256, 0, stream>>>(A, ATh, ATl);

    // ---- H = A A^T ----
    k_mm<0, false><<<dim3(m / 64, m / 128), 256, 0, stream>>>(
        nullptr, Ah, Al, Ah, Al, dd, m, nullptr, nullptr, nullptr, H,
        nullptr, nullptr);

    // ---- power iteration on H: eta = 1.8/lambda_max ----
    k_u0<<<m / 16, 256, 0, stream>>>(A, u);
    for (int it = 0; it < 9; ++it) {
        k_matvec<<<m / 16, 256, 0, stream>>>(H, u, wv);
        k_normalize<<<1, 1024, 0, stream>>>(wv, u);
    }
    k_matvec<<<m / 16, 256, 0, stream>>>(H, u, wv);  // z = H u9
    k_eta2<<<1, 1024, 0, stream>>>(wv, u, eta);

    // ---- M = I - eta*H (split f16) ----
    k_makeM<<<(m * m) / 1024, 256, 0, stream>>>(H, eta, Mh, Ml);

    // ---- r = eta*(x A^T - b); lam0 = relu(r) (split) ----
    k_mm<1, true><<<dim3(Bn / 64, m / 128), 256, 0, stream>>>(
        x, nullptr, nullptr, Ah, Al, dd, m, eta, b, nullptr, r, l0h, l0l);

    // ---- 29 iterations: lam <- relu(lam M + r) ----
    const _Float16 *pih = l0h, *pil = l0l;
    _Float16 *poh = l1h, *pol = l1l;
    for (int it = 0; it < 29; ++it) {
        k_mm<2, false><<<dim3(Bn / 64, m / 128), 256, 0, stream>>>(
            nullptr, pih, pil, Mh, Ml, m, m, nullptr, nullptr, r, nullptr,
            poh, pol);
        const _Float16* th = pih; const _Float16* tl = pil;
        pih = poh; pil = pol;
        poh = (_Float16*)th; pol = (_Float16*)tl;
    }

    // ---- out = x - lam A  (B-side = pre-split A^T) ----
    k_mm<3, false><<<dim3(Bn / 64, dd / 128), 256, 0, stream>>>(
        nullptr, pih, pil, ATh, ATl, m, dd, nullptr, nullptr, x, out,
        nullptr, nullptr);
}